// Round 6
// baseline (154.581 us; speedup 1.0000x reference)
//
#include <hip/hip_runtime.h>
#include <hip/hip_fp16.h>
#include <math.h>

#define NPTS 131072
#define KCOMP 256
#define DIM 32
#define KF 608                    // 576 quad features (4-aligned rows) + 32 m
#define PSIF_BYTES 311296         // 19456 granules * 16 B
#define WS_NEED (PSIF_BYTES + KCOMP * 4)

typedef __attribute__((ext_vector_type(8))) short short8;
typedef __attribute__((ext_vector_type(16))) float f32x16;

__device__ __forceinline__ unsigned short f2bf(float v) {
    unsigned u = __float_as_uint(v);
    u += 0x7fffu + ((u >> 16) & 1u);   // RNE
    return (unsigned short)(u >> 16);
}

// pack two f32 -> two bf16 (lo | hi<<16). RTN (+0x8000) + byte-perm: 3 ops.
__device__ __forceinline__ unsigned pkbf(float lo, float hi) {
#if __has_builtin(__builtin_amdgcn_perm)
    const unsigned a = __float_as_uint(hi) + 0x8000u;
    const unsigned b = __float_as_uint(lo) + 0x8000u;
    return __builtin_amdgcn_perm(a, b, 0x07060302u);
#else
    return (unsigned)f2bf(lo) | ((unsigned)f2bf(hi) << 16);
#endif
}

// async global->LDS DMA, 16 B/lane; LDS dest = wave-uniform base + lane*16.
__device__ __forceinline__ void dma16(const uint4* g, uint4* s) {
    __builtin_amdgcn_global_load_lds(
        (const __attribute__((address_space(1))) void*)g,
        (__attribute__((address_space(3))) void*)s, 16, 0, 0);
}

// LDS-only barrier: drain lgkmcnt but let global_load_lds (vmcnt) keep flying.
__device__ __forceinline__ void barrier_lds_only() {
    asm volatile("s_waitcnt lgkmcnt(0)\ns_barrier" ::: "memory");
}

// ---- compile-time feature decode: quad-packed triangular, 4-aligned rows ----
constexpr int L4c(int d) { return ((32 - d + 3) / 4) * 4; }
constexpr int PfxC(int d) { int s = 0; for (int i = 0; i < d; ++i) s += L4c(i); return s; }
constexpr int rowOfC(int p) { int d = 0; while (d < 31 && PfxC(d + 1) <= p) ++d; return d; }
constexpr int dOfC(int p) { return (p >= 576) ? -1 : rowOfC(p); }
constexpr int f0OfC(int p) {
    return (p >= 576) ? (p - 576) : ((rowOfC(p) & ~3) + (p - PfxC(rowOfC(p))));
}

// ---------------------------------------------------------------------------
// Precompute (unchanged from round 5 — verified correct)
// ---------------------------------------------------------------------------
__global__ __launch_bounds__(256) void gmm_pre(
    const float* __restrict__ S,
    const float* __restrict__ centers,
    const float* __restrict__ weights,
    unsigned short* __restrict__ PsiF,
    float* __restrict__ kc2)
{
    __shared__ float Sl[DIM][DIM + 1];
    __shared__ float As[DIM][DIM + 1];
    __shared__ float cl[DIM], ml[DIM];
    __shared__ float red[256];

    const int k = blockIdx.x, tid = threadIdx.x;

    for (int idx = tid; idx < DIM * DIM; idx += 256)
        Sl[idx >> 5][idx & 31] = S[(size_t)k * DIM * DIM + idx];
    if (tid < DIM) cl[tid] = centers[k * DIM + tid];
    __syncthreads();

    for (int idx = tid; idx < DIM * DIM; idx += 256) {
        const int d = idx >> 5, f = idx & 31;
        float a = 0.f;
#pragma unroll
        for (int e = 0; e < DIM; ++e) a = fmaf(Sl[d][e], Sl[f][e], a);
        As[d][f] = a;
    }
    __syncthreads();

    if (tid < DIM) {
        float mv = 0.f;
#pragma unroll
        for (int f = 0; f < DIM; ++f) mv = fmaf(As[tid][f], cl[f], mv);
        ml[tid] = mv;
    }
    __syncthreads();

    for (int p = tid; p < KF; p += 256) {
        float val;
        if (p < 576) {
            int d = 0, pr = 0;
            while (true) {
                const int len = ((32 - d + 3) >> 2) << 2;
                if (pr + len > p) break;
                pr += len; ++d;
            }
            const int f = (d & ~3) + (p - pr);
            val = (f < d) ? 0.f : ((f == d) ? -0.5f * As[d][d] : -As[d][f]);
        } else {
            val = ml[p - 576];
        }
        const int c = p >> 6, kk = p & 63;
        const int s = kk >> 4, qq = (kk >> 3) & 1, j = kk & 7;
        const int ct = k >> 5, ll = qq * 32 + (k & 31);
        const int g = c * 2048 + (s * 8 + ct) * 64 + ll;
        PsiF[(size_t)g * 8 + j] = f2bf(val);
    }

    red[tid] = fabsf(weights[tid]);
    __syncthreads();
    for (int off = 128; off > 0; off >>= 1) {
        if (tid < off) red[tid] += red[tid + off];
        __syncthreads();
    }
    const float wsum = red[0];

    for (int j = 0; j < DIM - 1; ++j) {
        const float inv = 1.0f / As[j][j];
        for (int idx = tid; idx < DIM * DIM; idx += 256) {
            const int r = idx >> 5, c = idx & 31;
            if (r > j && c > j)
                As[r][c] = fmaf(-As[r][j] * inv, As[j][c], As[r][c]);
        }
        __syncthreads();
    }

    if (tid < DIM) red[tid] = __logf(As[tid][tid]);
    __syncthreads();
    if (tid == 0) {
        float sl = 0.f;
        for (int j = 0; j < DIM; ++j) sl += red[j];
        float cac = 0.f;
        for (int d2 = 0; d2 < DIM; ++d2) cac = fmaf(ml[d2], cl[d2], cac);
        kc2[k] = __logf(fabsf(weights[k])) - __logf(wsum + 1e-30f)
               + 0.5f * sl - 0.5f * cac;
    }
}

// ---------------------------------------------------------------------------
// Main MFMA kernel: 512 threads / 8 waves, 64x64 wave tiles (64-AGPR acc),
// x fp16-packed in 16 VGPRs, B DMA double-buffered. 4 waves/SIMD target.
// ---------------------------------------------------------------------------
template<int IDX>
__device__ __forceinline__ float upk(const unsigned (&xp)[16]) {
    unsigned h = xp[IDX >> 1];
    if constexpr (IDX & 1) h >>= 16; else h &= 0xffffu;
    return __half2float(__builtin_bit_cast(__half, (unsigned short)h));
}

template<int P>
__device__ __forceinline__ void genQuad(const unsigned (&xp)[16], float* v) {
    constexpr int d = dOfC(P);
    constexpr int f0 = f0OfC(P);
    float xd = 1.f;
    if constexpr (d >= 0) xd = upk<d>(xp);
    const float a0 = upk<f0 + 0>(xp);
    const float a1 = upk<f0 + 1>(xp);
    const float a2 = upk<f0 + 2>(xp);
    const float a3 = upk<f0 + 3>(xp);
    v[0] = (d < 0) ? a0 : xd * a0;
    v[1] = (d < 0) ? a1 : xd * a1;
    v[2] = (d < 0) ? a2 : xd * a2;
    v[3] = (d < 0) ? a3 : xd * a3;
}

template<int C, int SS>
__device__ __forceinline__ void genSite(const unsigned (&xp)[16], uint4* sA4,
                                        int rbg, int r32) {
    float v[8];
    genQuad<C * 64 + SS * 8>(xp, v);
    genQuad<C * 64 + SS * 8 + 4>(xp, v + 4);
    uint4 u;
    u.x = pkbf(v[0], v[1]);
    u.y = pkbf(v[2], v[3]);
    u.z = pkbf(v[4], v[5]);
    u.w = pkbf(v[6], v[7]);
    sA4[(SS >> 1) * 256 + rbg * 64 + (SS & 1) * 32 + r32] = u;
}

template<int C>
__device__ __forceinline__ void doChunk(const unsigned (&xp)[16],
    uint4* sA4, uint4* sB4, const uint4* __restrict__ PsiF4,
    f32x16 (&acc)[2][2],
    int t, int l, int q2, int rbg, int r32, int rh, int cq)
{
    constexpr int NS  = (C < 9) ? 4 : 2;                   // K16-steps here
    constexpr int NSn = (C < 8) ? 4 : ((C == 8) ? 2 : 0);  // next chunk's

    if constexpr (C > 0) barrier_lds_only();   // sA(c-1) readers done
    // gen A(c) -> sA: 4 thread-groups (q2 = wave>>1, wave-uniform) x 2 sites
    switch (q2) {
    case 0: genSite<C, 0>(xp, sA4, rbg, r32);
            if constexpr (NS == 4) genSite<C, 4>(xp, sA4, rbg, r32); break;
    case 1: genSite<C, 1>(xp, sA4, rbg, r32);
            if constexpr (NS == 4) genSite<C, 5>(xp, sA4, rbg, r32); break;
    case 2: genSite<C, 2>(xp, sA4, rbg, r32);
            if constexpr (NS == 4) genSite<C, 6>(xp, sA4, rbg, r32); break;
    default: genSite<C, 3>(xp, sA4, rbg, r32);
            if constexpr (NS == 4) genSite<C, 7>(xp, sA4, rbg, r32); break;
    }
    __syncthreads();   // sA ready; drains DMA(c) (issued a full chunk ago)

    // issue DMA for chunk c+1 into the other buffer (zero VGPR staging)
    if constexpr (NSn > 0) {
        const uint4* src = PsiF4 + (C + 1) * 2048 + t;
        uint4* dst = sB4 + ((C + 1) & 1) * 2048 + t;
#pragma unroll
        for (int i = 0; i < NSn; ++i) dma16(src + i * 512, dst + i * 512);
    }

    const uint4* bb = sB4 + (C & 1) * 2048;
#pragma unroll
    for (int s = 0; s < NS; ++s) {
        short8 a0 = __builtin_bit_cast(short8, sA4[(s * 4 + rh * 2 + 0) * 64 + l]);
        short8 a1 = __builtin_bit_cast(short8, sA4[(s * 4 + rh * 2 + 1) * 64 + l]);
        short8 b0 = __builtin_bit_cast(short8, bb[(s * 8 + cq * 2 + 0) * 64 + l]);
        short8 b1 = __builtin_bit_cast(short8, bb[(s * 8 + cq * 2 + 1) * 64 + l]);
        acc[0][0] = __builtin_amdgcn_mfma_f32_32x32x16_bf16(a0, b0, acc[0][0], 0, 0, 0);
        acc[0][1] = __builtin_amdgcn_mfma_f32_32x32x16_bf16(a0, b1, acc[0][1], 0, 0, 0);
        acc[1][0] = __builtin_amdgcn_mfma_f32_32x32x16_bf16(a1, b0, acc[1][0], 0, 0, 0);
        acc[1][1] = __builtin_amdgcn_mfma_f32_32x32x16_bf16(a1, b1, acc[1][1], 0, 0, 0);
    }
}

__global__ __launch_bounds__(512, 4) void gmm_mfma(
    const float* __restrict__ points,
    const unsigned short* __restrict__ PsiF,
    const float* __restrict__ kc2,
    const float* __restrict__ thr,
    float* __restrict__ out)
{
    __shared__ uint4 sA4[1024];          // 16 KB: frag-ordered A chunk
    __shared__ uint4 sB4[4096];          // 64 KB: B double buffer (2 x 32 KB)
    // epilogue partials overlaid on sA4 (after barrier): 128 rows x 4 cq x 2
    float (*sPm)[4] = (float (*)[4])sA4;
    float (*sPs)[4] = (float (*)[4])(sA4 + 128);

    const int t = threadIdx.x;
    const int w = t >> 6, l = t & 63;
    const int row = t & 127, q2 = t >> 7;          // gen: 4 thread-groups/row
    const int rbg = row >> 5, r32 = row & 31;
    const int rh = w >> 2, cq = w & 3;             // wave tile: 64r x 64c

    const uint4* PsiF4 = (const uint4*)PsiF;

    // prologue DMA: chunk 0's B into buffer 0
    {
        const uint4* src = PsiF4 + t;
        uint4* dst = sB4 + t;
#pragma unroll
        for (int i = 0; i < 4; ++i) dma16(src + i * 512, dst + i * 512);
    }

    // load x, pack to fp16 pairs (16 VGPRs)
    unsigned xp[16];
    {
        const float4* px = (const float4*)(points + ((size_t)blockIdx.x * 128 + row) * DIM);
#pragma unroll
        for (int j2 = 0; j2 < 8; ++j2) {
            float4 v = px[j2];
            xp[2 * j2 + 0] = __builtin_bit_cast(unsigned, __floats2half2_rn(v.x, v.y));
            xp[2 * j2 + 1] = __builtin_bit_cast(unsigned, __floats2half2_rn(v.z, v.w));
        }
    }

    f32x16 acc[2][2];
#pragma unroll
    for (int a = 0; a < 2; ++a)
#pragma unroll
        for (int b = 0; b < 2; ++b)
#pragma unroll
            for (int r = 0; r < 16; ++r) acc[a][b][r] = 0.f;

    doChunk<0>(xp, sA4, sB4, PsiF4, acc, t, l, q2, rbg, r32, rh, cq);
    doChunk<1>(xp, sA4, sB4, PsiF4, acc, t, l, q2, rbg, r32, rh, cq);
    doChunk<2>(xp, sA4, sB4, PsiF4, acc, t, l, q2, rbg, r32, rh, cq);
    doChunk<3>(xp, sA4, sB4, PsiF4, acc, t, l, q2, rbg, r32, rh, cq);
    doChunk<4>(xp, sA4, sB4, PsiF4, acc, t, l, q2, rbg, r32, rh, cq);
    doChunk<5>(xp, sA4, sB4, PsiF4, acc, t, l, q2, rbg, r32, rh, cq);
    doChunk<6>(xp, sA4, sB4, PsiF4, acc, t, l, q2, rbg, r32, rh, cq);
    doChunk<7>(xp, sA4, sB4, PsiF4, acc, t, l, q2, rbg, r32, rh, cq);
    doChunk<8>(xp, sA4, sB4, PsiF4, acc, t, l, q2, rbg, r32, rh, cq);
    doChunk<9>(xp, sA4, sB4, PsiF4, acc, t, l, q2, rbg, r32, rh, cq);

    // epilogue: per-wave LSE over its 64 cols, partials to LDS, then combine
    float kcv[2];
#pragma unroll
    for (int j = 0; j < 2; ++j) kcv[j] = kc2[(cq * 2 + j) * 32 + (l & 31)];

    __syncthreads();                 // all sA readers done before overlay

#pragma unroll
    for (int rb = 0; rb < 2; ++rb) {
#pragma unroll
        for (int rg = 0; rg < 16; ++rg) {
            const float v0 = acc[rb][0][rg] + kcv[0];
            const float v1 = acc[rb][1][rg] + kcv[1];
            float m = fmaxf(v0, v1);
#pragma unroll
            for (int mask = 1; mask < 32; mask <<= 1)
                m = fmaxf(m, __shfl_xor(m, mask, 64));
            float sv = __expf(v0 - m) + __expf(v1 - m);
#pragma unroll
            for (int mask = 1; mask < 32; mask <<= 1)
                sv += __shfl_xor(sv, mask, 64);
            if ((l & 31) == 0) {
                const int R = rh * 64 + rb * 32 + (rg & 3) + 8 * (rg >> 2) + 4 * (l >> 5);
                sPm[R][cq] = m; sPs[R][cq] = sv;
            }
        }
    }
    __syncthreads();

    if (t < 128) {
        const float m0 = sPm[t][0], m1 = sPm[t][1];
        const float m2 = sPm[t][2], m3 = sPm[t][3];
        const float M = fmaxf(fmaxf(m0, m1), fmaxf(m2, m3));
        const float Sv = sPs[t][0] * __expf(m0 - M) + sPs[t][1] * __expf(m1 - M)
                       + sPs[t][2] * __expf(m2 - M) + sPs[t][3] * __expf(m3 - M);
        out[(size_t)blockIdx.x * 128 + t] = M + __logf(Sv) - thr[0];
    }
}

extern "C" void kernel_launch(void* const* d_in, const int* in_sizes, int n_in,
                              void* d_out, int out_size, void* d_ws, size_t ws_size,
                              hipStream_t stream) {
    const float* points  = (const float*)d_in[0];
    const float* centers = (const float*)d_in[1];
    const float* covs    = (const float*)d_in[2];
    const float* weights = (const float*)d_in[3];
    const float* thr     = (const float*)d_in[4];
    float* out = (float*)d_out;

    unsigned short* PsiF = (unsigned short*)d_ws;
    float* kc2 = (float*)((char*)d_ws + PSIF_BYTES);

    gmm_pre<<<KCOMP, 256, 0, stream>>>(covs, centers, weights, PsiF, kc2);
    gmm_mfma<<<NPTS / 128, 512, 0, stream>>>(points, PsiF, kc2, thr, out);
}